// Round 7
// baseline (107.237 us; speedup 1.0000x reference)
//
#include <hip/hip_runtime.h>
#include <math.h>

// Problem constants (fixed by the reference setup)
#define B_ 32
#define N_ 2048
#define D_ 64
#define R_ 32
#define T_ 31
#define O_ 12
#define HID_ 128
#define IN_DIM_ 63      // T_ + R_
#define NCH_ 32         // n-chunks for partial-U reduction (chunk = 64 rows)

// Workspace layout (float offsets)
#define OFF_UPART 0                              // B*NCH*R*D = 2,097,152
#define OFF_U     (OFF_UPART + B_*NCH_*R_*D_)    // + 65,536
#define OFF_CTX   (OFF_U + B_*R_*D_)             // + 1,024
#define OFF_PBF   (OFF_CTX + B_*R_)              // bf16 area: N*R ushort = 32,768 floats
#define OFF_SUT   (OFF_PBF + N_*R_/2)            // bf16 area: B*O*D*R ushort = 393,216 floats
// end ~ 2.59M floats ~ 10.4 MB (< ws)

typedef __attribute__((ext_vector_type(4))) float f32x4;
typedef __attribute__((ext_vector_type(8))) short short8;

__device__ __forceinline__ float softplus_f(float x) {
    return fmaxf(x, 0.0f) + log1pf(expf(-fabsf(x)));
}
__device__ __forceinline__ float gelu_f(float x) {
    return 0.5f * x * (1.0f + erff(x * 0.70710678118654752440f));
}
// float -> bf16 bits, round-to-nearest-even
__device__ __forceinline__ unsigned short f2bf(float f) {
    unsigned int u = __float_as_uint(f);
    u = (u + 0x7FFFu + ((u >> 16) & 1u)) >> 16;
    return (unsigned short)u;
}

// Kernel 1: partial U over n-chunks, softplus(Q) computed in-LDS (no global Qsp,
// no separate softplus kernel). b==0 blocks also emit Pbf = bf16(softplus(P_raw))
// for their n-chunk. grid = B_*NCH_ = 1024 blocks, 512 threads.
__global__ __launch_bounds__(512) void k_upart(const float* __restrict__ H,
                                               const float* __restrict__ Qr,
                                               const float* __restrict__ Pr,
                                               float* __restrict__ ws) {
    __shared__ float qs[64][R_];   // 8 KB: softplus(Q) rows n0..n0+63
    float* __restrict__ Upart = ws + OFF_UPART;
    int b = blockIdx.x / NCH_;
    int c = blockIdx.x % NCH_;
    int tid = threadIdx.x;
    const int n0 = c * 64;

    #pragma unroll
    for (int i = tid; i < 64 * R_; i += 512)
        qs[i >> 5][i & 31] = softplus_f(Qr[(size_t)n0 * R_ + i]);
    if (b == 0) {
        unsigned short* Pbf = (unsigned short*)(ws + OFF_PBF);
        #pragma unroll
        for (int i = tid; i < 64 * R_; i += 512)
            Pbf[(size_t)n0 * R_ + i] = f2bf(softplus_f(Pr[(size_t)n0 * R_ + i]));
    }
    __syncthreads();

    int d = tid & 63;
    int rb = __builtin_amdgcn_readfirstlane(tid >> 6);  // 0..7, wave-uniform
    const int r0 = rb * 4;
    float acc0 = 0.f, acc1 = 0.f, acc2 = 0.f, acc3 = 0.f;
    const float* __restrict__ Hb = H + ((size_t)b * N_ + n0) * D_ + d;
    #pragma unroll 2
    for (int i = 0; i < 64; ++i) {
        float h = Hb[(size_t)i * D_];
        acc0 = fmaf(h, qs[i][r0 + 0], acc0);   // uniform LDS addr -> broadcast
        acc1 = fmaf(h, qs[i][r0 + 1], acc1);
        acc2 = fmaf(h, qs[i][r0 + 2], acc2);
        acc3 = fmaf(h, qs[i][r0 + 3], acc3);
    }
    float* up = Upart + ((size_t)(b * NCH_ + c) * R_ + r0) * D_ + d;
    up[0 * D_] = acc0;
    up[1 * D_] = acc1;
    up[2 * D_] = acc2;
    up[3 * D_] = acc3;
}

// Kernel 2: reduce partials -> U, ctx = sqrt(mean_d U^2 + eps).
// grid (B_, 8) = 256 blocks (was 32 -> only 32 CUs active), 256 threads.
__global__ __launch_bounds__(256) void k_ured(float* __restrict__ ws) {
    const float* __restrict__ Upart = ws + OFF_UPART;
    float* __restrict__ U = ws + OFF_U;
    float* __restrict__ ctx = ws + OFF_CTX;
    int b = blockIdx.x;
    int r = blockIdx.y * 4 + (threadIdx.x >> 6);
    int d = threadIdx.x & 63;
    float u = 0.f;
    #pragma unroll 8
    for (int c = 0; c < NCH_; ++c)
        u += Upart[((size_t)(b * NCH_ + c) * R_ + r) * D_ + d];
    U[((size_t)b * R_ + r) * D_ + d] = u;
    float sq = u * u;
    #pragma unroll
    for (int off = 32; off; off >>= 1) sq += __shfl_xor(sq, off, 64);
    if (d == 0) ctx[b * R_ + r] = sqrtf(sq * (1.0f / D_) + 1e-6f);
}

// Kernel 3: MLP -> s, then SUT[b,o][d][r] = bf16(a * s[r] * U[b,r,d])
__global__ __launch_bounds__(128) void k_mlp(const float* __restrict__ ts_out,
                                             const float* __restrict__ W1,
                                             const float* __restrict__ b1,
                                             const float* __restrict__ W2,
                                             const float* __restrict__ b2,
                                             const float* __restrict__ alpha,
                                             float* __restrict__ ws) {
    __shared__ float feat[IN_DIM_];
    __shared__ float hsh[HID_];
    __shared__ float ssh[R_];
    int bo = blockIdx.x;
    int b = bo / O_;
    int tid = threadIdx.x;
    const float* __restrict__ ctx = ws + OFF_CTX;
    if (tid < T_) feat[tid] = ts_out[(size_t)bo * T_ + tid];
    else if (tid < IN_DIM_) feat[tid] = ctx[b * R_ + (tid - T_)];
    __syncthreads();
    float acc = b1[tid];
    #pragma unroll 9
    for (int k = 0; k < IN_DIM_; ++k) acc = fmaf(feat[k], W1[k * HID_ + tid], acc);
    hsh[tid] = gelu_f(acc);
    __syncthreads();
    if (tid < R_) {
        float a2 = b2[tid];
        #pragma unroll 8
        for (int j = 0; j < HID_; ++j) a2 = fmaf(hsh[j], W2[j * R_ + tid], a2);
        ssh[tid] = softplus_f(a2);
    }
    __syncthreads();
    float a = fminf(fmaxf(alpha[0], 0.0f), 1.0f);
    const float* __restrict__ U = ws + OFF_U;
    unsigned short* SUT = (unsigned short*)(ws + OFF_SUT) + (size_t)bo * D_ * R_;
    #pragma unroll
    for (int idx = tid; idx < D_ * R_; idx += 128) {
        int d = idx >> 5, r = idx & 31;
        SUT[idx] = f2bf(a * ssh[r] * U[((size_t)b * R_ + r) * D_ + d]);
    }
}

// Kernel 4 (MFMA, d-major output, nontemporal stores):
//   D[d][n] = sum_r SUT[b,o][d][r] * P[n][r];  out[b,o,n,d] = oma*H + D
// A-frag lane l: SUT[db*16+(l&15)][(l>>4)*8+j]; B-frag lane l: Pbf[n0+(l&15)][(l>>4)*8+j]
// D lane l: d = (l>>4)*4+j (consecutive), n = l&15 -> f32x4 store per (o,db).
// out is written once and never re-read -> nontemporal (don't thrash L2; keep
// SUT/H resident). grid (N/64, B), block 256.
__global__ __launch_bounds__(256) void k_main(const float* __restrict__ H,
                                              const float* __restrict__ alpha,
                                              const float* __restrict__ ws,
                                              float* __restrict__ out) {
    const int b = blockIdx.y;
    const int n0 = blockIdx.x * 64 + (threadIdx.x >> 6) * 16;
    const int lane = threadIdx.x & 63;
    const int l16 = lane & 15;
    const int lhi = lane >> 4;
    const float a = fminf(fmaxf(alpha[0], 0.0f), 1.0f);
    const float oma = 1.0f - a;

    const unsigned short* Pbf = (const unsigned short*)(ws + OFF_PBF);
    const unsigned short* SUT0 = (const unsigned short*)(ws + OFF_SUT);

    short8 pfrag = *(const short8*)(Pbf + (size_t)(n0 + l16) * R_ + lhi * 8);

    const float* __restrict__ Hrow = H + ((size_t)b * N_ + n0 + l16) * D_;
    f32x4 homa[4];
    #pragma unroll
    for (int db = 0; db < 4; ++db) {
        f32x4 hv = *(const f32x4*)(Hrow + db * 16 + lhi * 4);
        homa[db] = oma * hv;
    }

    float* __restrict__ oprow = out + ((size_t)(b * O_) * N_ + n0 + l16) * D_;

    #pragma unroll 2
    for (int o = 0; o < O_; ++o) {
        const unsigned short* SUT = SUT0 + (size_t)(b * O_ + o) * D_ * R_;
        float* __restrict__ op = oprow + (size_t)o * N_ * D_;
        #pragma unroll
        for (int db = 0; db < 4; ++db) {
            short8 sfrag = *(const short8*)(SUT + (size_t)(db * 16 + l16) * R_ + lhi * 8);
            f32x4 acc = __builtin_amdgcn_mfma_f32_16x16x32_bf16(
                sfrag, pfrag, (f32x4){0.f, 0.f, 0.f, 0.f}, 0, 0, 0);
            __builtin_nontemporal_store(homa[db] + acc, (f32x4*)(op + db * 16 + lhi * 4));
        }
    }
}

extern "C" void kernel_launch(void* const* d_in, const int* in_sizes, int n_in,
                              void* d_out, int out_size, void* d_ws, size_t ws_size,
                              hipStream_t stream) {
    const float* H      = (const float*)d_in[0];
    const float* ts_out = (const float*)d_in[1];
    // d_in[2] is O (int scalar) — shapes are compile-time constants here
    const float* P_raw  = (const float*)d_in[3];
    const float* Q_raw  = (const float*)d_in[4];
    const float* W1     = (const float*)d_in[5];
    const float* b1     = (const float*)d_in[6];
    const float* W2     = (const float*)d_in[7];
    const float* b2     = (const float*)d_in[8];
    const float* alpha  = (const float*)d_in[9];
    float* out = (float*)d_out;
    float* ws  = (float*)d_ws;

    // 1. partial U (softplus-Q in LDS; b==0 blocks also emit Pbf)
    k_upart<<<dim3(B_ * NCH_), dim3(512), 0, stream>>>(H, Q_raw, P_raw, ws);
    // 2. reduce U + ctx (256 blocks)
    k_ured<<<dim3(B_, 8), dim3(256), 0, stream>>>(ws);
    // 3. MLP -> s -> SUT (bf16, [d][r])
    k_mlp<<<dim3(B_ * O_), dim3(128), 0, stream>>>(ts_out, W1, b1, W2, b2, alpha, ws);
    // 4. main fused output via MFMA, d-major nontemporal stores
    k_main<<<dim3(N_ / 64, B_), dim3(256), 0, stream>>>(H, alpha, ws, out);
}

// Round 8
// 73.521 us; speedup vs baseline: 1.4586x; 1.4586x over previous
//
#include <hip/hip_runtime.h>
#include <math.h>

// Problem constants (fixed by the reference setup)
#define B_ 32
#define N_ 2048
#define D_ 64
#define R_ 32
#define T_ 31
#define O_ 12
#define HID_ 128
#define IN_DIM_ 63      // T_ + R_
#define NCH_ 32         // n-chunks for partial-U reduction

// Workspace layout (float offsets)
#define OFF_QSP   0
#define OFF_UPART (OFF_QSP + N_*R_)              // 65536
#define OFF_U     (OFF_UPART + B_*NCH_*R_*D_)    // 2162688
#define OFF_CTX   (OFF_U + B_*R_*D_)             // 2228224
#define OFF_PBF   (OFF_CTX + B_*R_)              // 2229248 (bf16 area, ushort*)
#define OFF_SUT   (OFF_PBF + N_*R_/2)            // 2262016 (bf16 area, ushort*)
// end ~ 2.65M floats ~ 10.6 MB (< ws)

typedef __attribute__((ext_vector_type(4))) float f32x4;
typedef __attribute__((ext_vector_type(8))) short short8;

__device__ __forceinline__ float softplus_f(float x) {
    return fmaxf(x, 0.0f) + log1pf(expf(-fabsf(x)));
}
__device__ __forceinline__ float gelu_f(float x) {
    return 0.5f * x * (1.0f + erff(x * 0.70710678118654752440f));
}
// float -> bf16 bits, round-to-nearest-even
__device__ __forceinline__ unsigned short f2bf(float f) {
    unsigned int u = __float_as_uint(f);
    u = (u + 0x7FFFu + ((u >> 16) & 1u)) >> 16;
    return (unsigned short)u;
}

// Kernel 1: Qsp = softplus(Q_raw) fp32 (s_load source for k_upart);
// Pbf = bf16(softplus(P_raw)). (R7 lesson: do NOT move this into k_upart's
// LDS — uniform ds_read broadcasts serialize the whole-CU LDS pipe.)
__global__ __launch_bounds__(256) void k_softplus(const float* __restrict__ Qr,
                                                  const float* __restrict__ Pr,
                                                  float* __restrict__ ws) {
    int i = blockIdx.x * blockDim.x + threadIdx.x;
    if (i < N_ * R_) {
        ws[OFF_QSP + i] = softplus_f(Qr[i]);
    } else if (i < 2 * N_ * R_) {
        int j = i - N_ * R_;
        ((unsigned short*)(ws + OFF_PBF))[j] = f2bf(softplus_f(Pr[j]));
    }
}

// Kernel 2a: partial U over n-chunks. grid = B_*NCH_ = 1024 blocks, 512 threads.
__global__ __launch_bounds__(512) void k_upart(const float* __restrict__ H,
                                               float* __restrict__ ws) {
    const float* __restrict__ Qsp = ws + OFF_QSP;
    float* __restrict__ Upart = ws + OFF_UPART;
    int b = blockIdx.x / NCH_;
    int c = blockIdx.x % NCH_;
    int tid = threadIdx.x;
    int d = tid & 63;
    int rb = __builtin_amdgcn_readfirstlane(tid >> 6);  // 0..7, wave-uniform
    const int r0 = rb * 4;
    float acc0 = 0.f, acc1 = 0.f, acc2 = 0.f, acc3 = 0.f;
    const int n0 = c * (N_ / NCH_);   // 64 rows per chunk
    const float* __restrict__ Hb = H + (size_t)b * N_ * D_ + d;
    #pragma unroll 2
    for (int i = 0; i < N_ / NCH_; ++i) {
        int n = n0 + i;
        float h = Hb[(size_t)n * D_];
        const float* q = Qsp + (size_t)n * R_ + r0;   // uniform -> s_load_dwordx4
        acc0 = fmaf(h, q[0], acc0);
        acc1 = fmaf(h, q[1], acc1);
        acc2 = fmaf(h, q[2], acc2);
        acc3 = fmaf(h, q[3], acc3);
    }
    float* up = Upart + ((size_t)(b * NCH_ + c) * R_ + r0) * D_ + d;
    up[0 * D_] = acc0;
    up[1 * D_] = acc1;
    up[2 * D_] = acc2;
    up[3 * D_] = acc3;
}

// Kernel 2b: reduce partials -> U, ctx = sqrt(mean_d U^2 + eps).
// grid (B_, 8) = 256 blocks, 256 threads (r = by*4 + wave).
__global__ __launch_bounds__(256) void k_ured(float* __restrict__ ws) {
    const float* __restrict__ Upart = ws + OFF_UPART;
    float* __restrict__ U = ws + OFF_U;
    float* __restrict__ ctx = ws + OFF_CTX;
    int b = blockIdx.x;
    int r = blockIdx.y * 4 + (threadIdx.x >> 6);
    int d = threadIdx.x & 63;
    float u = 0.f;
    #pragma unroll 8
    for (int c = 0; c < NCH_; ++c)
        u += Upart[((size_t)(b * NCH_ + c) * R_ + r) * D_ + d];
    U[((size_t)b * R_ + r) * D_ + d] = u;
    float sq = u * u;
    #pragma unroll
    for (int off = 32; off; off >>= 1) sq += __shfl_xor(sq, off, 64);
    if (d == 0) ctx[b * R_ + r] = sqrtf(sq * (1.0f / D_) + 1e-6f);
}

// Kernel 3: MLP -> s, then SUT[b,o][d][r] = bf16(a * s[r] * U[b,r,d])
__global__ __launch_bounds__(128) void k_mlp(const float* __restrict__ ts_out,
                                             const float* __restrict__ W1,
                                             const float* __restrict__ b1,
                                             const float* __restrict__ W2,
                                             const float* __restrict__ b2,
                                             const float* __restrict__ alpha,
                                             float* __restrict__ ws) {
    __shared__ float feat[IN_DIM_];
    __shared__ float hsh[HID_];
    __shared__ float ssh[R_];
    int bo = blockIdx.x;
    int b = bo / O_;
    int tid = threadIdx.x;
    const float* __restrict__ ctx = ws + OFF_CTX;
    if (tid < T_) feat[tid] = ts_out[(size_t)bo * T_ + tid];
    else if (tid < IN_DIM_) feat[tid] = ctx[b * R_ + (tid - T_)];
    __syncthreads();
    float acc = b1[tid];
    #pragma unroll 9
    for (int k = 0; k < IN_DIM_; ++k) acc = fmaf(feat[k], W1[k * HID_ + tid], acc);
    hsh[tid] = gelu_f(acc);
    __syncthreads();
    if (tid < R_) {
        float a2 = b2[tid];
        #pragma unroll 8
        for (int j = 0; j < HID_; ++j) a2 = fmaf(hsh[j], W2[j * R_ + tid], a2);
        ssh[tid] = softplus_f(a2);
    }
    __syncthreads();
    float a = fminf(fmaxf(alpha[0], 0.0f), 1.0f);
    const float* __restrict__ U = ws + OFF_U;
    unsigned short* SUT = (unsigned short*)(ws + OFF_SUT) + (size_t)bo * D_ * R_;
    #pragma unroll
    for (int idx = tid; idx < D_ * R_; idx += 128) {
        int d = idx >> 5, r = idx & 31;
        SUT[idx] = f2bf(a * ssh[r] * U[((size_t)b * R_ + r) * D_ + d]);
    }
}

// Kernel 4 (MFMA + LDS-transposed FULL-LINE stores):
//   D[d][n] = sum_r SUT[b,o][d][r] * P[n][r];  out[b,o,n,d] = oma*H + D
// MFMA layout identical to R6 (A=SUT d-tile, B=P rows, D: lane l -> d =
// db*16+lhi*4+j, n = nblk + w*16 + l16). Instead of storing 64B row-segments
// directly (suspected L2 write-allocate RFO: +201MB hidden reads), results go
// through a 16KB LDS tile [local n 64][d 64] with 16B-slot XOR swizzle
// (slot ^= rl&7), then stream out fully linearly: each wave-instr stores 1KB
// contiguous = 8 full 128B lines (same pattern as the 6.8TB/s fill).
// grid (N/64, B), block 256 (4 waves).
__global__ __launch_bounds__(256) void k_main(const float* __restrict__ H,
                                              const float* __restrict__ alpha,
                                              const float* __restrict__ ws,
                                              float* __restrict__ out) {
    __shared__ float tile[64 * 64];   // 16 KB
    const int b = blockIdx.y;
    const int nblk = blockIdx.x * 64;
    const int tid = threadIdx.x;
    const int w = tid >> 6;
    const int lane = tid & 63;
    const int l16 = lane & 15;
    const int lhi = lane >> 4;
    const int rl = w * 16 + l16;         // local n-row owned by this lane's D col
    const float a = fminf(fmaxf(alpha[0], 0.0f), 1.0f);
    const float oma = 1.0f - a;

    const unsigned short* Pbf = (const unsigned short*)(ws + OFF_PBF);
    const unsigned short* SUT0 = (const unsigned short*)(ws + OFF_SUT);

    // B-operand fragment: P row nblk+rl, k-slice lhi*8..+8
    short8 pfrag = *(const short8*)(Pbf + (size_t)(nblk + rl) * R_ + lhi * 8);

    // H row slice, pre-scaled: homa[db] = oma * H[nblk+rl][db*16 + lhi*4 ..+4]
    const float* __restrict__ Hrow = H + ((size_t)b * N_ + nblk + rl) * D_;
    f32x4 homa[4];
    #pragma unroll
    for (int db = 0; db < 4; ++db)
        homa[db] = oma * *(const f32x4*)(Hrow + db * 16 + lhi * 4);

    char* tbytes = (char*)tile;
    float* __restrict__ oblk = out + ((size_t)(b * O_) * N_ + nblk) * D_;

    for (int o = 0; o < O_; ++o) {
        const unsigned short* SUT = SUT0 + (size_t)(b * O_ + o) * D_ * R_;
        #pragma unroll
        for (int db = 0; db < 4; ++db) {
            short8 sfrag = *(const short8*)(SUT + (size_t)(db * 16 + l16) * R_ + lhi * 8);
            f32x4 v = homa[db] + __builtin_amdgcn_mfma_f32_16x16x32_bf16(
                sfrag, pfrag, (f32x4){0.f, 0.f, 0.f, 0.f}, 0, 0, 0);
            // ds_write_b128: row rl, byte col (db*64 + lhi*16), XOR-swizzled slot
            int c = (db * 64 + lhi * 16) ^ ((rl & 7) << 4);
            *(f32x4*)(tbytes + rl * 256 + c) = v;
        }
        __syncthreads();   // tile complete (implies lgkmcnt drain)
        char* op = (char*)(oblk + (size_t)o * N_ * D_);   // 16KB contiguous region
        #pragma unroll
        for (int i = 0; i < 4; ++i) {
            int g = i * 4096 + tid * 16;          // linear byte offset in tile
            int rr = g >> 8;
            int cc = (g & 255) ^ ((rr & 7) << 4);
            f32x4 v = *(const f32x4*)(tbytes + rr * 256 + cc);
            *(f32x4*)(op + g) = v;                // 1KB contiguous per wave-instr
        }
        __syncthreads();   // readers done before next o overwrites tile
    }
}

extern "C" void kernel_launch(void* const* d_in, const int* in_sizes, int n_in,
                              void* d_out, int out_size, void* d_ws, size_t ws_size,
                              hipStream_t stream) {
    const float* H      = (const float*)d_in[0];
    const float* ts_out = (const float*)d_in[1];
    // d_in[2] is O (int scalar) — shapes are compile-time constants here
    const float* P_raw  = (const float*)d_in[3];
    const float* Q_raw  = (const float*)d_in[4];
    const float* W1     = (const float*)d_in[5];
    const float* b1     = (const float*)d_in[6];
    const float* W2     = (const float*)d_in[7];
    const float* b2     = (const float*)d_in[8];
    const float* alpha  = (const float*)d_in[9];
    float* out = (float*)d_out;
    float* ws  = (float*)d_ws;

    // 1. softplus: Qsp fp32 + Pbf bf16
    k_softplus<<<dim3((2 * N_ * R_ + 255) / 256), dim3(256), 0, stream>>>(Q_raw, P_raw, ws);
    // 2a. partial U (1024 blocks -> 8 waves/SIMD)
    k_upart<<<dim3(B_ * NCH_), dim3(512), 0, stream>>>(H, ws);
    // 2b. reduce U + ctx (256 blocks)
    k_ured<<<dim3(B_, 8), dim3(256), 0, stream>>>(ws);
    // 3. MLP -> s -> SUT (bf16, [d][r])
    k_mlp<<<dim3(B_ * O_), dim3(128), 0, stream>>>(ts_out, W1, b1, W2, b2, alpha, ws);
    // 4. main fused output via MFMA + LDS-transposed linear stores
    k_main<<<dim3(N_ / 64, B_), dim3(256), 0, stream>>>(H, alpha, ws, out);
}